// Round 3
// baseline (23.036 us; speedup 1.0000x reference)
//
#include <hip/hip_runtime.h>

// MonotonicityLoss: loss = mean over pairs {same group, galloyl_i > galloyl_j}
// of relu(pred_i - pred_j + MARGIN)^2.
//
// R1: 16-byte hipMemsetAsync node cost ~39us/replay -> removed.
// R2: brute-force 67M pairs ~9us + finalize kernel + overhead = 22.8us.
// R3 (this): bucket by group (N_GROUPS=16) -> only ~4.2M same-group pairs
// (16x less), count computed exactly from a (group x galloyl) histogram,
// finalize fused into pairs kernel via last-block-done (counter zeroed by
// prep kernel every call -> poison-proof, replay-safe).

constexpr int   NG     = 16;    // N_GROUPS
constexpr int   NA     = 16;    // galloyl bin stride (values 0..11)
constexpr float MARGIN = 0.1f;

constexpr int NBLK_B   = 128;   // pairs-kernel grid: 16 groups x 4 ichunks x 2 jhalves
constexpr int MAXJ     = 512;   // per-block j-half cap (group size <= 1024)

// ---- d_ws layout (bytes) ----
//   0: double total          (zeroed by prep each call)
//   8: int    ctr            (zeroed by prep each call)
//  16: double count          (written by prep)
//  24: int    offs[17]
// 128: float  p_sorted[n]
// 128+4n: uchar g_sorted[n]

__global__ __launch_bounds__(1024)
void mono_prep_kernel(const float* __restrict__ pred,
                      const int*   __restrict__ gall,
                      const int*   __restrict__ grp,
                      int n, char* __restrict__ ws)
{
    __shared__ int       s_hga[NG * NA];   // group x galloyl histogram
    __shared__ int       s_off[NG + 1];
    __shared__ int       s_cur[NG];
    __shared__ long long s_cg[NG];         // per-group pair count

    double*        d_total = (double*)(ws + 0);
    int*           d_ctr   = (int*)   (ws + 8);
    double*        d_count = (double*)(ws + 16);
    int*           d_offs  = (int*)   (ws + 24);
    float*         ws_p    = (float*) (ws + 128);
    unsigned char* ws_g    = (unsigned char*)(ws + 128 + (size_t)4 * n);

    const int tid = threadIdx.x;

    if (tid < NG * NA) s_hga[tid] = 0;
    __syncthreads();

    // ---- histogram over (group, galloyl) ----
    for (int idx = tid; idx < n; idx += 1024) {
        const int g = grp[idx];
        const int a = gall[idx];
        atomicAdd(&s_hga[g * NA + a], 1);
    }
    __syncthreads();

    // ---- per-group size + exact eligible-pair count ----
    if (tid < NG) {
        int       pre = 0;
        long long cnt = 0;
        #pragma unroll
        for (int a = 0; a < 12; ++a) {
            const int h = s_hga[tid * NA + a];
            cnt += (long long)h * pre;   // pairs (a > b): n_a * sum_{b<a} n_b
            pre += h;
        }
        s_off[tid] = pre;   // temporarily: group size
        s_cg[tid]  = cnt;
    }
    __syncthreads();

    if (tid == 0) {
        int       off = 0;
        long long c   = 0;
        #pragma unroll
        for (int g = 0; g < NG; ++g) {
            const int sz = s_off[g];
            s_off[g] = off;
            d_offs[g] = off;
            off += sz;
            c += s_cg[g];
        }
        s_off[NG]  = off;
        d_offs[NG] = off;
        *d_count = (double)c;
        *d_total = 0.0;      // accumulator init for pairs kernel (replay-safe)
        *d_ctr   = 0;
    }
    __syncthreads();

    if (tid < NG) s_cur[tid] = s_off[tid];
    __syncthreads();

    // ---- counting-sort scatter by group ----
    for (int idx = tid; idx < n; idx += 1024) {
        const int g    = grp[idx];
        const int slot = atomicAdd(&s_cur[g], 1);
        ws_p[slot] = pred[idx];
        ws_g[slot] = (unsigned char)gall[idx];
    }
}

__global__ __launch_bounds__(256)
void mono_pairs_kernel(char* __restrict__ ws, int n, float* __restrict__ out)
{
    __shared__ float  s_p[MAXJ];
    __shared__ int    s_g[MAXJ];
    __shared__ double s_ws[4];

    double*              d_total = (double*)(ws + 0);
    int*                 d_ctr   = (int*)   (ws + 8);
    const double*        d_count = (const double*)(ws + 16);
    const int*           d_offs  = (const int*)   (ws + 24);
    const float*         ws_p    = (const float*) (ws + 128);
    const unsigned char* ws_g    = (const unsigned char*)(ws + 128 + (size_t)4 * n);

    const int tid  = threadIdx.x;
    const int bid  = blockIdx.x;
    const int g    = bid & 15;          // group
    const int rest = bid >> 4;
    const int ic   = rest & 3;          // i-chunk (256 each -> covers size<=1024)
    const int jh   = rest >> 2;         // j-half

    const int off0 = d_offs[g];
    const int size = d_offs[g + 1] - off0;

    const int jbeg = (jh == 0) ? 0 : (size >> 1);
    const int jend = (jh == 0) ? (size >> 1) : size;
    const int jn   = jend - jbeg;       // <= 512 since size <= 1024

    // stage this group's j-half
    for (int t = tid; t < jn; t += 256) {
        s_p[t] = ws_p[off0 + jbeg + t];
        s_g[t] = (int)ws_g[off0 + jbeg + t];
    }
    __syncthreads();

    // per-thread i
    const int  ii    = ic * 256 + tid;
    const bool valid = ii < size;
    float pim = 0.0f;
    int   gi  = -1;                     // never > s_g[t] (>=0)
    if (valid) {
        pim = ws_p[off0 + ii] + MARGIN;
        gi  = (int)ws_g[off0 + ii];
    }

    float vsum = 0.0f;
    #pragma unroll 8
    for (int t = 0; t < jn; ++t) {
        const int   sgj = s_g[t];       // uniform addr -> LDS broadcast
        const float spj = s_p[t];
        const bool  m   = gi > sgj;
        const float d   = pim - spj;
        float       r   = fmaxf(d, 0.0f);
        r = m ? r : 0.0f;
        vsum = fmaf(r, r, vsum);
    }

    // wave reduce (64 lanes) then block reduce
    double w = (double)vsum;
    for (int off = 32; off > 0; off >>= 1) w += __shfl_down(w, off);
    if ((tid & 63) == 0) s_ws[tid >> 6] = w;
    __syncthreads();

    if (tid == 0) {
        const double bs = s_ws[0] + s_ws[1] + s_ws[2] + s_ws[3];
        atomicAdd(d_total, bs);
        __threadfence();
        const int old = atomicAdd(d_ctr, 1);
        if (old == NBLK_B - 1) {        // last block: finalize
            const double tt = atomicAdd(d_total, 0.0);  // coherent read
            const double c  = *d_count;
            out[0] = (c > 0.0) ? (float)(tt / c) : 0.0f;
        }
    }
}

extern "C" void kernel_launch(void* const* d_in, const int* in_sizes, int n_in,
                              void* d_out, int out_size, void* d_ws, size_t ws_size,
                              hipStream_t stream)
{
    const float* pred = (const float*)d_in[0];
    const int*   gall = (const int*)d_in[1];
    const int*   grp  = (const int*)d_in[2];
    const int    n    = in_sizes[0];

    char* ws = (char*)d_ws;

    mono_prep_kernel<<<1, 1024, 0, stream>>>(pred, gall, grp, n, ws);
    mono_pairs_kernel<<<NBLK_B, 256, 0, stream>>>(ws, n, (float*)d_out);
}

// Round 4
// 20.452 us; speedup vs baseline: 1.1264x; 1.1264x over previous
//
#include <hip/hip_runtime.h>

// MonotonicityLoss: loss = mean over pairs {same group, galloyl_i > galloyl_j}
// of relu(pred_i - pred_j + MARGIN)^2.
//
// R1: 16-byte hipMemsetAsync node cost ~39us/replay -> removed (45.7->22.8).
// R3: serial 1-block prep (sort by group) swapped pair-work for latency; net 0.
// R4 (this): no prep dispatch. Each block compacts its own group into LDS
// (inputs are L2-resident; 16x duplicated streaming is ~free), then same-group
// pairs only. 2 dispatches total: fused compute -> per-block partials
// (overwritten, no init needed) + 1-wave finalize.

constexpr int   NG     = 16;            // N_GROUPS
constexpr int   NIC    = 4;             // i-chunks of 256
constexpr int   NJQ    = 4;             // j-quarters of 256
constexpr int   NBLK   = NG * NIC * NJQ; // 256 blocks -> 1/CU
constexpr int   CAP    = 1024;          // per-group LDS capacity (mean 512, sd ~22)
constexpr float MARGIN = 0.1f;

__global__ __launch_bounds__(256)
void mono_fused_kernel(const float* __restrict__ pred,
                       const int*   __restrict__ gall,
                       const int*   __restrict__ grp,
                       int n,
                       double*    __restrict__ part_sum,
                       long long* __restrict__ part_cnt)
{
    __shared__ int2   s_pg[CAP];        // .x = pred bits, .y = galloyl
    __shared__ int    s_cnt;
    __shared__ double s_ws[4];
    __shared__ int    s_wc[4];

    const int tid = threadIdx.x;
    const int bid = blockIdx.x;
    const int g   = bid & (NG - 1);     // group
    const int ic  = (bid >> 4) & (NIC - 1);
    const int jq  = bid >> 6;

    if (tid == 0) s_cnt = 0;
    __syncthreads();

    // ---- compact this block's group into LDS (coalesced stream, L2-hit) ----
    for (int idx = tid; idx < n; idx += 256) {
        const int   gg = grp[idx];
        const float p  = pred[idx];
        const int   a  = gall[idx];
        if (gg == g) {
            const int slot = atomicAdd(&s_cnt, 1);
            if (slot < CAP) s_pg[slot] = make_int2(__float_as_int(p), a);
        }
    }
    __syncthreads();

    const int size = min(s_cnt, CAP);
    const int jbeg = jq * 256;
    const int jend = min(jbeg + 256, size);

    // ---- per-thread i (from the same compacted array) ----
    const int ii  = ic * 256 + tid;
    float pim = 0.0f;
    int   gi  = -1;                     // sentinel: never > gall_j (>=0)
    if (ii < size) {
        const int2 v = s_pg[ii];
        pim = __int_as_float(v.x) + MARGIN;
        gi  = v.y;
    }

    float vsum = 0.0f;
    int   vcnt = 0;
    #pragma unroll 8
    for (int t = jbeg; t < jend; ++t) {
        const int2  v = s_pg[t];        // uniform addr -> LDS broadcast, 1x b64
        const bool  m = gi > v.y;
        const float d = pim - __int_as_float(v.x);
        float       r = fmaxf(d, 0.0f);
        r = m ? r : 0.0f;
        vsum = fmaf(r, r, vsum);
        vcnt += (int)m;
    }

    // ---- wave (64) + block reduction -> per-block partial slot ----
    double w = (double)vsum;
    int    c = vcnt;
    for (int off = 32; off > 0; off >>= 1) {
        w += __shfl_down(w, off);
        c += __shfl_down(c, off);
    }
    if ((tid & 63) == 0) { s_ws[tid >> 6] = w; s_wc[tid >> 6] = c; }
    __syncthreads();
    if (tid == 0) {
        part_sum[bid] = s_ws[0] + s_ws[1] + s_ws[2] + s_ws[3];
        part_cnt[bid] = (long long)(s_wc[0] + s_wc[1] + s_wc[2] + s_wc[3]);
    }
}

__global__ __launch_bounds__(64)
void mono_finalize_kernel(const double* __restrict__ part_sum,
                          const long long* __restrict__ part_cnt,
                          float* __restrict__ out)
{
    const int tid = threadIdx.x;
    double    ts = 0.0;
    long long tc = 0;
    #pragma unroll
    for (int p = 0; p < NBLK / 64; ++p) {    // 4 partials per lane
        ts += part_sum[tid + p * 64];
        tc += part_cnt[tid + p * 64];
    }
    for (int off = 32; off > 0; off >>= 1) {
        ts += __shfl_down(ts, off);
        tc += __shfl_down(tc, off);
    }
    if (tid == 0)
        out[0] = (tc > 0) ? (float)(ts / (double)tc) : 0.0f;
}

extern "C" void kernel_launch(void* const* d_in, const int* in_sizes, int n_in,
                              void* d_out, int out_size, void* d_ws, size_t ws_size,
                              hipStream_t stream)
{
    const float* pred = (const float*)d_in[0];
    const int*   gall = (const int*)d_in[1];
    const int*   grp  = (const int*)d_in[2];
    const int    n    = in_sizes[0];

    double*    part_sum = (double*)d_ws;
    long long* part_cnt = (long long*)((char*)d_ws + NBLK * sizeof(double));

    mono_fused_kernel<<<NBLK, 256, 0, stream>>>(pred, gall, grp, n,
                                                part_sum, part_cnt);
    mono_finalize_kernel<<<1, 64, 0, stream>>>(part_sum, part_cnt, (float*)d_out);
}